// Round 20
// baseline (44.433 us; speedup 1.0000x reference)
//
#include <hip/hip_runtime.h>
#include <math.h>

#define TT 1024
#define DD 128

static constexpr float kNegInf = -1e9f;

typedef __fp16 h2 __attribute__((ext_vector_type(2)));

__device__ __forceinline__ unsigned int pk16(float a, float b) {
  h2 v = __builtin_amdgcn_cvt_pkrtz(a, b);
  return __builtin_bit_cast(unsigned int, v);
}
__device__ __forceinline__ float dot2f(unsigned int a, unsigned int b, float c) {
#if __has_builtin(__builtin_amdgcn_fdot2)
  return __builtin_amdgcn_fdot2(__builtin_bit_cast(h2, a),
                                __builtin_bit_cast(h2, b), c, false);
#else
  h2 av = __builtin_bit_cast(h2, a), bv = __builtin_bit_cast(h2, b);
  return c + (float)av.x * (float)bv.x + (float)av.y * (float)bv.y;
#endif
}

// ---- K0: transpose f32 [d][j], f16 j-pair pack [jp][d], swj/bias ----
__global__ __launch_bounds__(256) void k_prep(const float* __restrict__ h,
                                              const float* __restrict__ w,
                                              const int* __restrict__ mk,
                                              float* __restrict__ hTf,
                                              unsigned int* __restrict__ hT16,
                                              float* __restrict__ swj,
                                              float* __restrict__ bias) {
  __shared__ __align__(16) float tile[32][132];
  __shared__ float wred[32][8];
  const int b  = blockIdx.x >> 5;
  const int jt = blockIdx.x & 31;
  const int tid = threadIdx.x;
  const float4* src = (const float4*)h + (size_t)(b * TT + jt * 32) * 32;
#pragma unroll
  for (int k = 0; k < 4; ++k) {
    int idx = k * 256 + tid;             // 0..1023
    float4 v = src[idx];
    int j = idx >> 5, c = idx & 31;
    *((float4*)&tile[j][c * 4]) = v;
  }
  __syncthreads();
  // hTf[d][j]
#pragma unroll
  for (int k = 0; k < 4; ++k) {
    int idx = k * 256 + tid;             // 0..1023
    int d = idx >> 3, jq = idx & 7;
    float4 v = {tile[jq * 4 + 0][d], tile[jq * 4 + 1][d],
                tile[jq * 4 + 2][d], tile[jq * 4 + 3][d]};
    *(float4*)&hTf[(size_t)(b * DD + d) * TT + jt * 32 + jq * 4] = v;
  }
  // hT16[jp][d]
#pragma unroll
  for (int k = 0; k < 2; ++k) {
    int idx = k * 256 + tid;             // 0..511
    int jp = idx >> 5, dq = idx & 31;
    uint4 wv;
    wv.x = pk16(tile[jp * 2][dq * 4 + 0], tile[jp * 2 + 1][dq * 4 + 0]);
    wv.y = pk16(tile[jp * 2][dq * 4 + 1], tile[jp * 2 + 1][dq * 4 + 1]);
    wv.z = pk16(tile[jp * 2][dq * 4 + 2], tile[jp * 2 + 1][dq * 4 + 2]);
    wv.w = pk16(tile[jp * 2][dq * 4 + 3], tile[jp * 2 + 1][dq * 4 + 3]);
    *(uint4*)&hT16[((size_t)(b * 512 + jt * 16 + jp)) * DD + dq * 4] = wv;
  }
  // wj
  {
    const int j = tid & 31, dg = tid >> 5;
    float p = 0.f;
#pragma unroll
    for (int e = 0; e < 16; e += 4) {
      float4 hv = *(const float4*)&tile[j][dg * 16 + e];
      float4 wv = *(const float4*)&w[dg * 16 + e];
      p += hv.x * wv.x + hv.y * wv.y + hv.z * wv.z + hv.w * wv.w;
    }
    wred[j][dg] = p;
  }
  __syncthreads();
  if (tid < 32) {
    const int row = b * TT + jt * 32 + tid;
    float a = 0.f;
#pragma unroll
    for (int e = 0; e < 8; ++e) a += wred[tid][e];
    const bool ok = (mk[row] != 0);
    swj[row]  = ok ? -a : 0.f;
    bias[row] = ok ? 0.f : kNegInf;
  }
}

// ---- K1: symmetric score kernel — upper triangle only, writes S both ways.
// Block = 4-row panel rp x 512-j half, trapezoid-clipped to j >= 4*rp.
// grid = 2 batches x (128 jh0-blocks + 256 jh1-blocks) = 768 blocks.
__global__ __launch_bounds__(256) void k_score(
    const float* __restrict__ h, const float* __restrict__ hTf,
    const float* __restrict__ swj, const float* __restrict__ bias,
    float* __restrict__ S) {
  __shared__ __align__(16) float A_lds[4][DD];   // 2 KB

  const int tid = threadIdx.x;
  int t = blockIdx.x;
  const int b = (t >= 384) ? 1 : 0;
  t -= b * 384;
  const int jh = (t < 128) ? 0 : 1;
  const int rp = (t < 128) ? t : (t - 128);
  const int i0 = rp * 4;
  const int off = (jh == 0) ? i0 : ((i0 > 512) ? (i0 - 512) : 0);
  const int jstart = jh * 512 + off;
  const int nq = (512 - off) >> 2;               // active j-quads
  const int rot = blockIdx.x & 31;

  // stage the 4 A-rows (512 floats)
  {
    const float2 v = *(const float2*)(h + ((size_t)b * TT + i0) * DD + tid * 2);
    *(float2*)&A_lds[0][tid * 2] = v;
  }
  __syncthreads();

  const int q  = tid & 127;                      // quad index
  const int g2 = (tid >> 7) * 2;                 // row base within panel (0/2)
  if (q >= nq) return;
  const int j = jstart + q * 4;
  const float* Bb = hTf + (size_t)b * DD * TT + j;

  float acc[4][2];                               // [u(j)][r(row)]
#pragma unroll
  for (int u = 0; u < 4; ++u) { acc[u][0] = 0.f; acc[u][1] = 0.f; }

#define PS(s) (((s) + rot) & 31)
#define LOADB4(B, s) {                                        \
    B[0] = *(const float4*)(Bb + (size_t)((s) * 4 + 0) * TT); \
    B[1] = *(const float4*)(Bb + (size_t)((s) * 4 + 1) * TT); \
    B[2] = *(const float4*)(Bb + (size_t)((s) * 4 + 2) * TT); \
    B[3] = *(const float4*)(Bb + (size_t)((s) * 4 + 3) * TT); }
#define COMP2(B, s) {                                                  \
    const float4 A0 = *(const float4*)&A_lds[g2][(s) * 4];             \
    const float4 A1 = *(const float4*)&A_lds[g2 + 1][(s) * 4];         \
    _Pragma("unroll") for (int e = 0; e < 4; ++e) {                    \
      const float a0 = (e == 0) ? A0.x : (e == 1) ? A0.y               \
                       : (e == 2) ? A0.z : A0.w;                       \
      const float a1 = (e == 0) ? A1.x : (e == 1) ? A1.y               \
                       : (e == 2) ? A1.z : A1.w;                       \
      acc[0][0] += fabsf(a0 - B[e].x); acc[0][1] += fabsf(a1 - B[e].x);\
      acc[1][0] += fabsf(a0 - B[e].y); acc[1][1] += fabsf(a1 - B[e].y);\
      acc[2][0] += fabsf(a0 - B[e].z); acc[2][1] += fabsf(a1 - B[e].z);\
      acc[3][0] += fabsf(a0 - B[e].w); acc[3][1] += fabsf(a1 - B[e].w);\
    } }

  {
    float4 B0[4], B1[4];
    LOADB4(B0, PS(0));
#pragma unroll 1
    for (int s = 0; s < 16; ++s) {
      const int p1 = PS(2 * s + 1);
      const int p0 = PS(2 * s);
      LOADB4(B1, p1);
      COMP2(B0, p0);
      if (s < 15) LOADB4(B0, PS(2 * s + 2));
      COMP2(B1, p1);
    }
  }

  // direct scores: S[i][j..j+3] for the 2 rows, using swj/bias of column j
  const float4 swv = *(const float4*)(swj + (size_t)b * TT + j);
  const float4 bvv = *(const float4*)(bias + (size_t)b * TT + j);
  float* Sb = S + (size_t)b * TT * TT;
#pragma unroll
  for (int r = 0; r < 2; ++r) {
    float4 dv;
    dv.x = fmaf(swv.x, acc[0][r], bvv.x);
    dv.y = fmaf(swv.y, acc[1][r], bvv.y);
    dv.z = fmaf(swv.z, acc[2][r], bvv.z);
    dv.w = fmaf(swv.w, acc[3][r], bvv.w);
    *(float4*)&Sb[(size_t)(i0 + g2 + r) * TT + j] = dv;
  }
  // transposed scores: S[j+u][i..i+1], using swj/bias of column i (the row)
  const float swi0 = swj[b * TT + i0 + g2];
  const float swi1 = swj[b * TT + i0 + g2 + 1];
  const float bii0 = bias[b * TT + i0 + g2];
  const float bii1 = bias[b * TT + i0 + g2 + 1];
#pragma unroll
  for (int u = 0; u < 4; ++u) {
    float2 tv;
    tv.x = fmaf(swi0, acc[u][0], bii0);
    tv.y = fmaf(swi1, acc[u][1], bii1);
    *(float2*)&Sb[(size_t)(j + u) * TT + i0 + g2] = tv;
  }
}

// ---- K2: softmax + PV + concat; block = 4 rows x full 1024 j ----
__global__ __launch_bounds__(256, 2) void k_sm(
    const float* __restrict__ h, const float* __restrict__ S,
    const unsigned int* __restrict__ hT16, float* __restrict__ out) {
  __shared__ __align__(16) float A_lds[4][DD];       // 2 KB
  __shared__ __align__(16) unsigned int Pt[512][4];  // 8 KB [q][row]
  __shared__ __align__(16) float ctxp[4][4][DD];     // 8 KB [slice][row][d]
  __shared__ float redm[4][4];
  __shared__ float redl[4][4];

  const int tid  = threadIdx.x;
  const int lane = tid & 63;
  const int wv   = tid >> 6;
  const int b    = blockIdx.x >> 8;
  const int row0 = (blockIdx.x & 255) * 4;
  const int rot  = blockIdx.x & 31;

  {
    const float2 v = *(const float2*)(h + ((size_t)b * TT + row0) * DD + tid * 2);
    *(float2*)&A_lds[0][tid * 2] = v;
  }
  __syncthreads();

  // read scores for this thread's j-quad x 4 rows (coalesced b128)
  const int j = tid * 4;
  const float* Sb = S + ((size_t)b * TT + row0) * TT;
  float sc[4][4];                                  // [u][r]
#pragma unroll
  for (int r = 0; r < 4; ++r) {
    const float4 sv = *(const float4*)&Sb[(size_t)r * TT + j];
    sc[0][r] = sv.x; sc[1][r] = sv.y; sc[2][r] = sv.z; sc[3][r] = sv.w;
  }

  // row max over full 1024 j
  {
    float mr[4];
#pragma unroll
    for (int r = 0; r < 4; ++r) {
      float m0 = fmaxf(fmaxf(sc[0][r], sc[1][r]), fmaxf(sc[2][r], sc[3][r]));
#pragma unroll
      for (int off = 32; off; off >>= 1) m0 = fmaxf(m0, __shfl_xor(m0, off));
      mr[r] = m0;
    }
    if (lane == 0) {
#pragma unroll
      for (int r = 0; r < 4; ++r) redm[wv][r] = mr[r];
    }
  }
  __syncthreads();
  float M[4];
#pragma unroll
  for (int r = 0; r < 4; ++r)
    M[r] = fmaxf(fmaxf(redm[0][r], redm[1][r]),
                 fmaxf(redm[2][r], redm[3][r]));

  // exp + pack P j-pairs + sums
  {
    float p[4][4];
    float ls[4] = {0.f, 0.f, 0.f, 0.f};
#pragma unroll
    for (int u = 0; u < 4; ++u)
#pragma unroll
      for (int r = 0; r < 4; ++r) {
        p[u][r] = __expf(sc[u][r] - M[r]);
        ls[r] += p[u][r];
      }
    uint4 w0 = {pk16(p[0][0], p[1][0]), pk16(p[0][1], p[1][1]),
                pk16(p[0][2], p[1][2]), pk16(p[0][3], p[1][3])};
    uint4 w1 = {pk16(p[2][0], p[3][0]), pk16(p[2][1], p[3][1]),
                pk16(p[2][2], p[3][2]), pk16(p[2][3], p[3][3])};
    *(uint4*)&Pt[tid * 2 + 0][0] = w0;
    *(uint4*)&Pt[tid * 2 + 1][0] = w1;
#pragma unroll
    for (int r = 0; r < 4; ++r) {
#pragma unroll
      for (int off = 32; off; off >>= 1) ls[r] += __shfl_xor(ls[r], off);
    }
    if (lane == 0) {
#pragma unroll
      for (int r = 0; r < 4; ++r) redl[wv][r] = ls[r];
    }
  }
  __syncthreads();

  // PV: thread = (dpair 0..63) x (slice 0..3)
  const int dp = tid & 63;
  const int s  = tid >> 6;
  const unsigned int* Vp =
      hT16 + ((size_t)(b * 512 + s * 128)) * DD + dp * 2;
  float cx[4][2];
#pragma unroll
  for (int r = 0; r < 4; ++r) { cx[r][0] = 0.f; cx[r][1] = 0.f; }
  const int qrot = rot * 4;
#pragma unroll 4
  for (int qq = 0; qq < 128; ++qq) {
    const int q = (qq + qrot) & 127;
    const uint4 P = *(const uint4*)&Pt[s * 128 + q][0];
    const uint2 V = *(const uint2*)(Vp + (size_t)q * DD);
    cx[0][0] = dot2f(P.x, V.x, cx[0][0]); cx[0][1] = dot2f(P.x, V.y, cx[0][1]);
    cx[1][0] = dot2f(P.y, V.x, cx[1][0]); cx[1][1] = dot2f(P.y, V.y, cx[1][1]);
    cx[2][0] = dot2f(P.z, V.x, cx[2][0]); cx[2][1] = dot2f(P.z, V.y, cx[2][1]);
    cx[3][0] = dot2f(P.w, V.x, cx[3][0]); cx[3][1] = dot2f(P.w, V.y, cx[3][1]);
  }
#pragma unroll
  for (int r = 0; r < 4; ++r)
    *(float2*)&ctxp[s][r][dp * 2] = make_float2(cx[r][0], cx[r][1]);
  __syncthreads();

  // epilogue
#pragma unroll
  for (int k = 0; k < 2; ++k) {
    const int idx = tid + k * 256;
    const int r = idx >> 7, d = idx & 127;
    const float L = redl[0][r] + redl[1][r] + redl[2][r] + redl[3][r];
    const float c = (ctxp[0][r][d] + ctxp[1][r][d]) +
                    (ctxp[2][r][d] + ctxp[3][r][d]);
    const size_t row = (size_t)blockIdx.x * 4 + r;
    out[row * 256 + d]       = A_lds[r][d];
    out[row * 256 + 128 + d] = c / L;
  }
}

extern "C" void kernel_launch(void* const* d_in, const int* in_sizes, int n_in,
                              void* d_out, int out_size, void* d_ws, size_t ws_size,
                              hipStream_t stream) {
  const float* h  = (const float*)d_in[0];
  const int*   mk = (const int*)d_in[1];
  const float* w  = (const float*)d_in[2];
  float* out = (float*)d_out;

  char* ws = (char*)d_ws;
  float*        swj  = (float*)ws;                              // 8 KB
  float*        bias = (float*)(ws + 8192);                     // 8 KB
  float*        hTf  = (float*)(ws + 16384);                    // 1 MB
  unsigned int* hT16 = (unsigned int*)(ws + 16384 + 1048576);   // 512 KB
  float*        S    = (float*)(ws + 16384 + 1048576 + 524288); // 8 MB

  hipLaunchKernelGGL(k_prep,  dim3(64),  dim3(256), 0, stream,
                     h, w, mk, hTf, hT16, swj, bias);
  hipLaunchKernelGGL(k_score, dim3(768), dim3(256), 0, stream,
                     h, hTf, swj, bias, S);
  hipLaunchKernelGGL(k_sm,    dim3(512), dim3(256), 0, stream,
                     h, S, hT16, out);
}

// Round 21
// 40.305 us; speedup vs baseline: 1.1024x; 1.1024x over previous
//
#include <hip/hip_runtime.h>
#include <math.h>

#define TT 1024
#define DD 128

static constexpr float kNegInf = -1e9f;

typedef __fp16 h2 __attribute__((ext_vector_type(2)));

__device__ __forceinline__ unsigned int pk16(float a, float b) {
  h2 v = __builtin_amdgcn_cvt_pkrtz(a, b);
  return __builtin_bit_cast(unsigned int, v);
}
__device__ __forceinline__ float dot2f(unsigned int a, unsigned int b, float c) {
#if __has_builtin(__builtin_amdgcn_fdot2)
  return __builtin_amdgcn_fdot2(__builtin_bit_cast(h2, a),
                                __builtin_bit_cast(h2, b), c, false);
#else
  h2 av = __builtin_bit_cast(h2, a), bv = __builtin_bit_cast(h2, b);
  return c + (float)av.x * (float)bv.x + (float)av.y * (float)bv.y;
#endif
}

// ---- K0: transpose f32 [d][j], f16 j-pair pack [jp][d], swj/bias ----
__global__ __launch_bounds__(256) void k_prep(const float* __restrict__ h,
                                              const float* __restrict__ w,
                                              const int* __restrict__ mk,
                                              float* __restrict__ hTf,
                                              unsigned int* __restrict__ hT16,
                                              float* __restrict__ swj,
                                              float* __restrict__ bias) {
  __shared__ __align__(16) float tile[32][132];
  __shared__ float wred[32][8];
  const int b  = blockIdx.x >> 5;
  const int jt = blockIdx.x & 31;
  const int tid = threadIdx.x;
  const float4* src = (const float4*)h + (size_t)(b * TT + jt * 32) * 32;
#pragma unroll
  for (int k = 0; k < 4; ++k) {
    int idx = k * 256 + tid;             // 0..1023
    float4 v = src[idx];
    int j = idx >> 5, c = idx & 31;
    *((float4*)&tile[j][c * 4]) = v;
  }
  __syncthreads();
  // hTf[d][j]
#pragma unroll
  for (int k = 0; k < 4; ++k) {
    int idx = k * 256 + tid;             // 0..1023
    int d = idx >> 3, jq = idx & 7;
    float4 v = {tile[jq * 4 + 0][d], tile[jq * 4 + 1][d],
                tile[jq * 4 + 2][d], tile[jq * 4 + 3][d]};
    *(float4*)&hTf[(size_t)(b * DD + d) * TT + jt * 32 + jq * 4] = v;
  }
  // hT16[jp][d]
#pragma unroll
  for (int k = 0; k < 2; ++k) {
    int idx = k * 256 + tid;             // 0..511
    int jp = idx >> 5, dq = idx & 31;
    uint4 wv;
    wv.x = pk16(tile[jp * 2][dq * 4 + 0], tile[jp * 2 + 1][dq * 4 + 0]);
    wv.y = pk16(tile[jp * 2][dq * 4 + 1], tile[jp * 2 + 1][dq * 4 + 1]);
    wv.z = pk16(tile[jp * 2][dq * 4 + 2], tile[jp * 2 + 1][dq * 4 + 2]);
    wv.w = pk16(tile[jp * 2][dq * 4 + 3], tile[jp * 2 + 1][dq * 4 + 3]);
    *(uint4*)&hT16[((size_t)(b * 512 + jt * 16 + jp)) * DD + dq * 4] = wv;
  }
  // wj
  {
    const int j = tid & 31, dg = tid >> 5;
    float p = 0.f;
#pragma unroll
    for (int e = 0; e < 16; e += 4) {
      float4 hv = *(const float4*)&tile[j][dg * 16 + e];
      float4 wv = *(const float4*)&w[dg * 16 + e];
      p += hv.x * wv.x + hv.y * wv.y + hv.z * wv.z + hv.w * wv.w;
    }
    wred[j][dg] = p;
  }
  __syncthreads();
  if (tid < 32) {
    const int row = b * TT + jt * 32 + tid;
    float a = 0.f;
#pragma unroll
    for (int e = 0; e < 8; ++e) a += wred[tid][e];
    const bool ok = (mk[row] != 0);
    swj[row]  = ok ? -a : 0.f;
    bias[row] = ok ? 0.f : kNegInf;
  }
}

// ---- K1: block = 8 rows x FULL 1024 j; 512 thr; thread = J4 x R4 ----
// grid = 256 blocks (1/CU). B-stream shared by 2 row-halves -> L2 traffic /2.
__global__ __launch_bounds__(512, 2) void k_fused(
    const float* __restrict__ h, const float* __restrict__ hTf,
    const unsigned int* __restrict__ hT16,
    const float* __restrict__ swj, const float* __restrict__ bias,
    float* __restrict__ out) {
  __shared__ __align__(16) float A_lds[8][DD];       // 4 KB
  __shared__ __align__(16) unsigned int Pt[512][8];  // 16 KB [jp][row]
  __shared__ __align__(16) float ctxp[4][8][DD];     // 16 KB [slice][row][d]
  __shared__ float redm[8][4];                       // [wave][local row]
  __shared__ float redl[8][4];

  const int tid  = threadIdx.x;
  const int lane = tid & 63;
  const int wv   = tid >> 6;                // 0..7
  const int rh   = tid >> 8;                // row-half 0/1
  const int b    = blockIdx.x >> 7;
  const int row0 = (blockIdx.x & 127) * 8;  // row within batch
  const int rot  = blockIdx.x & 31;

  // stage 8 A-rows into LDS (1024 floats, float2 per thread)
  {
    const float2 v = *(const float2*)(h + ((size_t)b * TT + row0) * DD + tid * 2);
    *(float2*)&A_lds[0][tid * 2] = v;
  }
  __syncthreads();

  // ---------------- phase 1: distances, J=4 x R=4, explicit dbuf --------
  const int q = tid & 255;                  // j-quad id
  const int j = q * 4;
  const float* Bb = hTf + (size_t)b * DD * TT + j;
  const int ar = rh * 4;                    // this thread's A-row base
  float acc[4][4];
#pragma unroll
  for (int u = 0; u < 4; ++u)
#pragma unroll
    for (int r = 0; r < 4; ++r) acc[u][r] = 0.f;

#define PS(s) (((s) + rot) & 31)

#define LOADB4(B, s) {                                        \
    B[0] = *(const float4*)(Bb + (size_t)((s) * 4 + 0) * TT); \
    B[1] = *(const float4*)(Bb + (size_t)((s) * 4 + 1) * TT); \
    B[2] = *(const float4*)(Bb + (size_t)((s) * 4 + 2) * TT); \
    B[3] = *(const float4*)(Bb + (size_t)((s) * 4 + 3) * TT); }

#define COMP4(B, s) {                                                  \
    _Pragma("unroll") for (int r = 0; r < 4; ++r) {                    \
      const float4 Ar = *(const float4*)&A_lds[ar + r][(s) * 4];       \
      _Pragma("unroll") for (int e = 0; e < 4; ++e) {                  \
        const float a = (e == 0) ? Ar.x : (e == 1) ? Ar.y              \
                        : (e == 2) ? Ar.z : Ar.w;                      \
        acc[0][r] += fabsf(a - B[e].x);                                \
        acc[1][r] += fabsf(a - B[e].y);                                \
        acc[2][r] += fabsf(a - B[e].z);                                \
        acc[3][r] += fabsf(a - B[e].w);                                \
      } } }

  {
    float4 B0[4], B1[4];
    LOADB4(B0, PS(0));
#pragma unroll 1
    for (int s = 0; s < 16; ++s) {
      const int p1 = PS(2 * s + 1);
      const int p0 = PS(2 * s);
      LOADB4(B1, p1);                    // unconditional
      COMP4(B0, p0);
      if (s < 15) LOADB4(B0, PS(2 * s + 2));
      COMP4(B1, p1);
    }
  }

  // scores
  const float4 swv = *(const float4*)(swj + (size_t)b * TT + j);
  const float4 bvv = *(const float4*)(bias + (size_t)b * TT + j);
  float sc[4][4];
#pragma unroll
  for (int r = 0; r < 4; ++r) {
    sc[0][r] = fmaf(swv.x, acc[0][r], bvv.x);
    sc[1][r] = fmaf(swv.y, acc[1][r], bvv.y);
    sc[2][r] = fmaf(swv.z, acc[2][r], bvv.z);
    sc[3][r] = fmaf(swv.w, acc[3][r], bvv.w);
  }

  // row max over full 1024 j (4 waves per row-half)
  {
    float mr[4];
#pragma unroll
    for (int r = 0; r < 4; ++r) {
      float m0 = fmaxf(fmaxf(sc[0][r], sc[1][r]), fmaxf(sc[2][r], sc[3][r]));
#pragma unroll
      for (int off = 32; off; off >>= 1) m0 = fmaxf(m0, __shfl_xor(m0, off));
      mr[r] = m0;
    }
    if (lane == 0) {
#pragma unroll
      for (int r = 0; r < 4; ++r) redm[wv][r] = mr[r];
    }
  }
  __syncthreads();
  float M[4];
#pragma unroll
  for (int r = 0; r < 4; ++r)
    M[r] = fmaxf(fmaxf(redm[rh * 4 + 0][r], redm[rh * 4 + 1][r]),
                 fmaxf(redm[rh * 4 + 2][r], redm[rh * 4 + 3][r]));

  // exp + pack P j-pairs + sums
  {
    float p[4][4];
    float ls[4] = {0.f, 0.f, 0.f, 0.f};
#pragma unroll
    for (int u = 0; u < 4; ++u)
#pragma unroll
      for (int r = 0; r < 4; ++r) {
        p[u][r] = __expf(sc[u][r] - M[r]);
        ls[r] += p[u][r];
      }
    uint4 w0 = {pk16(p[0][0], p[1][0]), pk16(p[0][1], p[1][1]),
                pk16(p[0][2], p[1][2]), pk16(p[0][3], p[1][3])};
    uint4 w1 = {pk16(p[2][0], p[3][0]), pk16(p[2][1], p[3][1]),
                pk16(p[2][2], p[3][2]), pk16(p[2][3], p[3][3])};
    *(uint4*)&Pt[2 * q + 0][rh * 4] = w0;
    *(uint4*)&Pt[2 * q + 1][rh * 4] = w1;
#pragma unroll
    for (int r = 0; r < 4; ++r) {
#pragma unroll
      for (int off = 32; off; off >>= 1) ls[r] += __shfl_xor(ls[r], off);
    }
    if (lane == 0) {
#pragma unroll
      for (int r = 0; r < 4; ++r) redl[wv][r] = ls[r];
    }
  }
  __syncthreads();

  // ---------------- PV: thread = (dpair, rowhalf, slice 0..3) ------------
  const int dp  = tid & 63;
  const int rh2 = (tid >> 6) & 1;
  const int s   = tid >> 7;                 // 0..3, 128 jp each
  const unsigned int* Vp =
      hT16 + ((size_t)(b * 512 + s * 128)) * DD + dp * 2;
  float cx[4][2];
#pragma unroll
  for (int r = 0; r < 4; ++r) { cx[r][0] = 0.f; cx[r][1] = 0.f; }
  const int qrot = rot * 4;
#pragma unroll 4
  for (int qq = 0; qq < 128; ++qq) {
    const int qi = (qq + qrot) & 127;
    const uint4 P = *(const uint4*)&Pt[s * 128 + qi][rh2 * 4];  // LDS b128
    const uint2 V = *(const uint2*)(Vp + (size_t)qi * DD);      // coalesced
    cx[0][0] = dot2f(P.x, V.x, cx[0][0]); cx[0][1] = dot2f(P.x, V.y, cx[0][1]);
    cx[1][0] = dot2f(P.y, V.x, cx[1][0]); cx[1][1] = dot2f(P.y, V.y, cx[1][1]);
    cx[2][0] = dot2f(P.z, V.x, cx[2][0]); cx[2][1] = dot2f(P.z, V.y, cx[2][1]);
    cx[3][0] = dot2f(P.w, V.x, cx[3][0]); cx[3][1] = dot2f(P.w, V.y, cx[3][1]);
  }
#pragma unroll
  for (int r = 0; r < 4; ++r)
    *(float2*)&ctxp[s][rh2 * 4 + r][dp * 2] = make_float2(cx[r][0], cx[r][1]);
  __syncthreads();

  // ---------------- epilogue: reduce slices, normalize, concat ----------
#pragma unroll
  for (int k = 0; k < 2; ++k) {
    const int idx = tid + k * 512;        // 0..1023
    const int r = idx >> 7, d = idx & 127;
    const int hb = (r >> 2) * 4, rr = r & 3;
    const float L = redl[hb + 0][rr] + redl[hb + 1][rr] +
                    redl[hb + 2][rr] + redl[hb + 3][rr];
    const float c = (ctxp[0][r][d] + ctxp[1][r][d]) +
                    (ctxp[2][r][d] + ctxp[3][r][d]);
    const size_t row = (size_t)blockIdx.x * 8 + r;
    out[row * 256 + d]       = A_lds[r][d];
    out[row * 256 + 128 + d] = c / L;
  }
}

extern "C" void kernel_launch(void* const* d_in, const int* in_sizes, int n_in,
                              void* d_out, int out_size, void* d_ws, size_t ws_size,
                              hipStream_t stream) {
  const float* h  = (const float*)d_in[0];
  const int*   mk = (const int*)d_in[1];
  const float* w  = (const float*)d_in[2];
  float* out = (float*)d_out;

  char* ws = (char*)d_ws;
  float*        swj  = (float*)ws;                              // 8 KB
  float*        bias = (float*)(ws + 8192);                     // 8 KB
  float*        hTf  = (float*)(ws + 16384);                    // 1 MB
  unsigned int* hT16 = (unsigned int*)(ws + 16384 + 1048576);   // 512 KB

  hipLaunchKernelGGL(k_prep,  dim3(64),  dim3(256), 0, stream,
                     h, w, mk, hTf, hT16, swj, bias);
  hipLaunchKernelGGL(k_fused, dim3(256), dim3(512), 0, stream,
                     h, hTf, hT16, swj, bias, out);
}

// Round 22
// 35.403 us; speedup vs baseline: 1.2550x; 1.1385x over previous
//
#include <hip/hip_runtime.h>
#include <math.h>

#define TT 1024
#define DD 128

static constexpr float kNegInf = -1e9f;

typedef __fp16 h2 __attribute__((ext_vector_type(2)));

__device__ __forceinline__ unsigned int pk16(float a, float b) {
  h2 v = __builtin_amdgcn_cvt_pkrtz(a, b);
  return __builtin_bit_cast(unsigned int, v);
}
__device__ __forceinline__ unsigned int pkrne(float a, float b) {
  h2 v; v.x = (__fp16)a; v.y = (__fp16)b;   // v_cvt_f16_f32 (RNE) x2 + pack
  return __builtin_bit_cast(unsigned int, v);
}
__device__ __forceinline__ float dot2f(unsigned int a, unsigned int b, float c) {
#if __has_builtin(__builtin_amdgcn_fdot2)
  return __builtin_amdgcn_fdot2(__builtin_bit_cast(h2, a),
                                __builtin_bit_cast(h2, b), c, false);
#else
  h2 av = __builtin_bit_cast(h2, a), bv = __builtin_bit_cast(h2, b);
  return c + (float)av.x * (float)bv.x + (float)av.y * (float)bv.y;
#endif
}
// acc += |a0-b0| + |a1-b1| for f16 pairs: pk_sub + and-mask abs + dot2 with (1,1)
__device__ __forceinline__ float absdot(unsigned int a, unsigned int b, float c) {
  h2 d = __builtin_bit_cast(h2, a) - __builtin_bit_cast(h2, b);
  unsigned int ad = __builtin_bit_cast(unsigned int, d) & 0x7FFF7FFFu;
  return dot2f(ad, 0x3C003C00u, c);
}

// ---- K0: f16 dim-pair layout hTd16[d2][j], f16 j-pair pack hT16[jp][d],
//          swj/bias. 64 blocks x 256 thr.
__global__ __launch_bounds__(256) void k_prep(const float* __restrict__ h,
                                              const float* __restrict__ w,
                                              const int* __restrict__ mk,
                                              unsigned int* __restrict__ hTd16,
                                              unsigned int* __restrict__ hT16,
                                              float* __restrict__ swj,
                                              float* __restrict__ bias) {
  __shared__ __align__(16) float tile[32][132];
  __shared__ float wred[32][8];
  const int b  = blockIdx.x >> 5;
  const int jt = blockIdx.x & 31;
  const int tid = threadIdx.x;
  const float4* src = (const float4*)h + (size_t)(b * TT + jt * 32) * 32;
#pragma unroll
  for (int k = 0; k < 4; ++k) {
    int idx = k * 256 + tid;             // 0..1023
    float4 v = src[idx];
    int j = idx >> 5, c = idx & 31;
    *((float4*)&tile[j][c * 4]) = v;
  }
  __syncthreads();
  // hTd16[d2][j]: word = (f16(h[j][2d2]), f16(h[j][2d2+1])), RNE
#pragma unroll
  for (int k = 0; k < 8; ++k) {
    int idx = k * 256 + tid;             // 0..2047
    int d2 = idx >> 5, jl = idx & 31;
    hTd16[((size_t)(b * 64 + d2)) * TT + jt * 32 + jl] =
        pkrne(tile[jl][2 * d2], tile[jl][2 * d2 + 1]);
  }
  // hT16[jp][d] (PV V-operand)
#pragma unroll
  for (int k = 0; k < 2; ++k) {
    int idx = k * 256 + tid;             // 0..511
    int jp = idx >> 5, dq = idx & 31;
    uint4 wv;
    wv.x = pk16(tile[jp * 2][dq * 4 + 0], tile[jp * 2 + 1][dq * 4 + 0]);
    wv.y = pk16(tile[jp * 2][dq * 4 + 1], tile[jp * 2 + 1][dq * 4 + 1]);
    wv.z = pk16(tile[jp * 2][dq * 4 + 2], tile[jp * 2 + 1][dq * 4 + 2]);
    wv.w = pk16(tile[jp * 2][dq * 4 + 3], tile[jp * 2 + 1][dq * 4 + 3]);
    *(uint4*)&hT16[((size_t)(b * 512 + jt * 16 + jp)) * DD + dq * 4] = wv;
  }
  // wj
  {
    const int j = tid & 31, dg = tid >> 5;
    float p = 0.f;
#pragma unroll
    for (int e = 0; e < 16; e += 4) {
      float4 hv = *(const float4*)&tile[j][dg * 16 + e];
      float4 wv = *(const float4*)&w[dg * 16 + e];
      p += hv.x * wv.x + hv.y * wv.y + hv.z * wv.z + hv.w * wv.w;
    }
    wred[j][dg] = p;
  }
  __syncthreads();
  if (tid < 32) {
    const int row = b * TT + jt * 32 + tid;
    float a = 0.f;
#pragma unroll
    for (int e = 0; e < 8; ++e) a += wred[tid][e];
    const bool ok = (mk[row] != 0);
    swj[row]  = ok ? -a : 0.f;
    bias[row] = ok ? 0.f : kNegInf;
  }
}

// ---- K1: block = 8 rows x FULL 1024 j; 512 thr; f16-pk distance ----
__global__ __launch_bounds__(512, 2) void k_fused(
    const float* __restrict__ h, const unsigned int* __restrict__ hTd16,
    const unsigned int* __restrict__ hT16,
    const float* __restrict__ swj, const float* __restrict__ bias,
    float* __restrict__ out) {
  __shared__ __align__(16) unsigned int A16[8][64];  // 2 KB [row][d2]
  __shared__ __align__(16) unsigned int Pt[512][8];  // 16 KB [jp][row]
  __shared__ __align__(16) float ctxp[4][8][DD];     // 16 KB [slice][row][d]
  __shared__ float redm[8][4];
  __shared__ float redl[8][4];

  const int tid  = threadIdx.x;
  const int lane = tid & 63;
  const int wv   = tid >> 6;                // 0..7
  const int rh   = tid >> 8;                // row-half 0/1
  const int b    = blockIdx.x >> 7;
  const int row0 = (blockIdx.x & 127) * 8;
  const int rot  = blockIdx.x & 15;

  // stage 8 A-rows as f16 dim-pair words (one word per thread)
  {
    const int r = tid >> 6, d2 = tid & 63;
    const float2 av =
        *(const float2*)(h + ((size_t)b * TT + row0 + r) * DD + 2 * d2);
    A16[r][d2] = pkrne(av.x, av.y);
  }
  __syncthreads();

  // ---------------- phase 1: distances, f16-pk, J=4 x R=4, dbuf ---------
  const int q = tid & 255;                  // j-quad id
  const int j = q * 4;
  const unsigned int* Bb = hTd16 + (size_t)b * 64 * TT + j;
  const int ar = rh * 4;
  float acc[4][4];                          // [u(j)][r(row)]
#pragma unroll
  for (int u = 0; u < 4; ++u)
#pragma unroll
    for (int r = 0; r < 4; ++r) acc[u][r] = 0.f;

#define PS(s) (((s) + rot) & 15)

// step s covers dim-pairs 4s..4s+3; each uint4 = 4 j at one dim-pair
#define LOADB16(B, s) {                                       \
    B[0] = *(const uint4*)(Bb + (size_t)((s) * 4 + 0) * TT);  \
    B[1] = *(const uint4*)(Bb + (size_t)((s) * 4 + 1) * TT);  \
    B[2] = *(const uint4*)(Bb + (size_t)((s) * 4 + 2) * TT);  \
    B[3] = *(const uint4*)(Bb + (size_t)((s) * 4 + 3) * TT); }

#define COMP16(B, s) {                                                 \
    _Pragma("unroll") for (int r = 0; r < 4; ++r) {                    \
      const uint4 aw = *(const uint4*)&A16[ar + r][(s) * 4];           \
      _Pragma("unroll") for (int dl = 0; dl < 4; ++dl) {               \
        const unsigned int a = (dl == 0) ? aw.x : (dl == 1) ? aw.y     \
                               : (dl == 2) ? aw.z : aw.w;              \
        acc[0][r] = absdot(a, B[dl].x, acc[0][r]);                     \
        acc[1][r] = absdot(a, B[dl].y, acc[1][r]);                     \
        acc[2][r] = absdot(a, B[dl].z, acc[2][r]);                     \
        acc[3][r] = absdot(a, B[dl].w, acc[3][r]);                     \
      } } }

  {
    uint4 B0[4], B1[4];
    LOADB16(B0, PS(0));
#pragma unroll 1
    for (int s = 0; s < 8; ++s) {
      const int p1 = PS(2 * s + 1);
      const int p0 = PS(2 * s);
      LOADB16(B1, p1);                   // unconditional
      COMP16(B0, p0);
      if (s < 7) LOADB16(B0, PS(2 * s + 2));
      COMP16(B1, p1);
    }
  }

  // scores
  const float4 swv = *(const float4*)(swj + (size_t)b * TT + j);
  const float4 bvv = *(const float4*)(bias + (size_t)b * TT + j);
  float sc[4][4];
#pragma unroll
  for (int r = 0; r < 4; ++r) {
    sc[0][r] = fmaf(swv.x, acc[0][r], bvv.x);
    sc[1][r] = fmaf(swv.y, acc[1][r], bvv.y);
    sc[2][r] = fmaf(swv.z, acc[2][r], bvv.z);
    sc[3][r] = fmaf(swv.w, acc[3][r], bvv.w);
  }

  // row max over full 1024 j (4 waves per row-half)
  {
    float mr[4];
#pragma unroll
    for (int r = 0; r < 4; ++r) {
      float m0 = fmaxf(fmaxf(sc[0][r], sc[1][r]), fmaxf(sc[2][r], sc[3][r]));
#pragma unroll
      for (int off = 32; off; off >>= 1) m0 = fmaxf(m0, __shfl_xor(m0, off));
      mr[r] = m0;
    }
    if (lane == 0) {
#pragma unroll
      for (int r = 0; r < 4; ++r) redm[wv][r] = mr[r];
    }
  }
  __syncthreads();
  float M[4];
#pragma unroll
  for (int r = 0; r < 4; ++r)
    M[r] = fmaxf(fmaxf(redm[rh * 4 + 0][r], redm[rh * 4 + 1][r]),
                 fmaxf(redm[rh * 4 + 2][r], redm[rh * 4 + 3][r]));

  // exp + pack P j-pairs + sums
  {
    float p[4][4];
    float ls[4] = {0.f, 0.f, 0.f, 0.f};
#pragma unroll
    for (int u = 0; u < 4; ++u)
#pragma unroll
      for (int r = 0; r < 4; ++r) {
        p[u][r] = __expf(sc[u][r] - M[r]);
        ls[r] += p[u][r];
      }
    uint4 w0 = {pk16(p[0][0], p[1][0]), pk16(p[0][1], p[1][1]),
                pk16(p[0][2], p[1][2]), pk16(p[0][3], p[1][3])};
    uint4 w1 = {pk16(p[2][0], p[3][0]), pk16(p[2][1], p[3][1]),
                pk16(p[2][2], p[3][2]), pk16(p[2][3], p[3][3])};
    *(uint4*)&Pt[2 * q + 0][rh * 4] = w0;
    *(uint4*)&Pt[2 * q + 1][rh * 4] = w1;
#pragma unroll
    for (int r = 0; r < 4; ++r) {
#pragma unroll
      for (int off = 32; off; off >>= 1) ls[r] += __shfl_xor(ls[r], off);
    }
    if (lane == 0) {
#pragma unroll
      for (int r = 0; r < 4; ++r) redl[wv][r] = ls[r];
    }
  }
  __syncthreads();

  // ---------------- PV: thread = (dpair, rowhalf, slice 0..3) ------------
  const int dp  = tid & 63;
  const int rh2 = (tid >> 6) & 1;
  const int s   = tid >> 7;                 // 0..3, 128 jp each
  const unsigned int* Vp =
      hT16 + ((size_t)(b * 512 + s * 128)) * DD + dp * 2;
  float cx[4][2];
#pragma unroll
  for (int r = 0; r < 4; ++r) { cx[r][0] = 0.f; cx[r][1] = 0.f; }
  const int qrot = rot * 8;
#pragma unroll 4
  for (int qq = 0; qq < 128; ++qq) {
    const int qi = (qq + qrot) & 127;
    const uint4 P = *(const uint4*)&Pt[s * 128 + qi][rh2 * 4];
    const uint2 V = *(const uint2*)(Vp + (size_t)qi * DD);
    cx[0][0] = dot2f(P.x, V.x, cx[0][0]); cx[0][1] = dot2f(P.x, V.y, cx[0][1]);
    cx[1][0] = dot2f(P.y, V.x, cx[1][0]); cx[1][1] = dot2f(P.y, V.y, cx[1][1]);
    cx[2][0] = dot2f(P.z, V.x, cx[2][0]); cx[2][1] = dot2f(P.z, V.y, cx[2][1]);
    cx[3][0] = dot2f(P.w, V.x, cx[3][0]); cx[3][1] = dot2f(P.w, V.y, cx[3][1]);
  }
#pragma unroll
  for (int r = 0; r < 4; ++r)
    *(float2*)&ctxp[s][rh2 * 4 + r][dp * 2] = make_float2(cx[r][0], cx[r][1]);
  __syncthreads();

  // ---------------- epilogue: reduce slices, normalize, concat ----------
#pragma unroll
  for (int k = 0; k < 2; ++k) {
    const int idx = tid + k * 512;        // 0..1023
    const int r = idx >> 7, d = idx & 127;
    const int hb = (r >> 2) * 4, rr = r & 3;
    const float L = redl[hb + 0][rr] + redl[hb + 1][rr] +
                    redl[hb + 2][rr] + redl[hb + 3][rr];
    const float c = (ctxp[0][r][d] + ctxp[1][r][d]) +
                    (ctxp[2][r][d] + ctxp[3][r][d]);
    const size_t row = (size_t)blockIdx.x * 8 + r;
    out[row * 256 + d]       = h[row * DD + d];
    out[row * 256 + 128 + d] = c / L;
  }
}

extern "C" void kernel_launch(void* const* d_in, const int* in_sizes, int n_in,
                              void* d_out, int out_size, void* d_ws, size_t ws_size,
                              hipStream_t stream) {
  const float* h  = (const float*)d_in[0];
  const int*   mk = (const int*)d_in[1];
  const float* w  = (const float*)d_in[2];
  float* out = (float*)d_out;

  char* ws = (char*)d_ws;
  float*        swj   = (float*)ws;                              // 8 KB
  float*        bias  = (float*)(ws + 8192);                     // 8 KB
  unsigned int* hTd16 = (unsigned int*)(ws + 16384);             // 512 KB
  unsigned int* hT16  = (unsigned int*)(ws + 16384 + 524288);    // 512 KB

  hipLaunchKernelGGL(k_prep,  dim3(64),  dim3(256), 0, stream,
                     h, w, mk, hTd16, hT16, swj, bias);
  hipLaunchKernelGGL(k_fused, dim3(256), dim3(512), 0, stream,
                     h, hTd16, hT16, swj, bias, out);
}